// Round 1
// baseline (401.219 us; speedup 1.0000x reference)
//
#include <hip/hip_runtime.h>
#include <stdint.h>

typedef uint32_t u32;
typedef uint16_t u16;

static constexpr int M_DIM = 8192;
static constexpr int N_DIM = 1024;
static constexpr int K_DIM = 4096;

// gemm geometry: 256x128 tile, BK=64, 1 block/CU, both operands through LDS
static constexpr int BM = 256;
static constexpr int BN = 128;
static constexpr int BK = 64;
static constexpr int KT64 = K_DIM / BK;          // 64 k-tiles
static constexpr int K_TILES32 = K_DIM / 32;     // 128 32-k fragments along K
static constexpr int MB_TILES = M_DIM / 16;      // 512
static constexpr int NB_TILES = N_DIM / 16;      // 64

// fragment = 16 rows x 32 k fp16 in exact MFMA lane order: 64 lanes x 16 B = 1 KiB
static constexpr size_t FRAG_U16 = 512;
static constexpr size_t HT_BYTES = (size_t)MB_TILES * K_TILES32 * FRAG_U16 * 2;  // 64 MiB
static constexpr size_t WT_BYTES = (size_t)NB_TILES * K_TILES32 * FRAG_U16 * 2;  // 8 MiB
static constexpr size_t WS_NEEDED = HT_BYTES + WT_BYTES;                         // 72 MiB

typedef __attribute__((ext_vector_type(8))) _Float16 half8;  // MFMA A/B frag (4 VGPRs)
typedef __attribute__((ext_vector_type(4))) float f32x4;     // MFMA C/D frag

__device__ __forceinline__ u32 pack2(float a, float b) {
  union { _Float16 h[2]; u32 u; } p;
  p.h[0] = (_Float16)a;   // v_cvt_f16_f32, RNE
  p.h[1] = (_Float16)b;
  return p.u;
}

// GELU via Abramowitz-Stegun 7.1.26 erf (|err| <= 1.5e-7) + dropout keep-mask * 1/(1-0.1).
__device__ __forceinline__ float gelu_drop(float x, u32 keep) {
  float ax = fabsf(x);
  float z  = ax * 0.70710678f;
  float t  = __builtin_amdgcn_rcpf(fmaf(0.3275911f, z, 1.0f));
  float poly = fmaf(fmaf(fmaf(fmaf(1.061405429f, t, -1.453152027f),
                              t, 1.421413741f),
                         t, -0.284496736f),
                    t, 0.254829592f) * t;
  float e   = exp2f(z * z * -1.44269504f);    // exp(-z^2)
  float erf = fmaf(-poly, e, 1.0f);           // erf(|x|/sqrt(2)) in [0,1)
  float g   = 0.5f * x * (1.0f + copysignf(erf, x));
  return keep ? g * 1.1111112f : 0.0f;
}

__device__ __forceinline__ void async_cp16(const void* g, void* l) {
  __builtin_amdgcn_global_load_lds((__attribute__((address_space(1))) u32*)g,
                                   (__attribute__((address_space(3))) u32*)l,
                                   16, 0, 0);
}

// ---------------- pass 1: fragment-major pack, kt-PAIR per wave ----------------
// Each wave now handles 2 consecutive 32-k fragments of one 16-row block:
// lane reads 64 B contiguous per stream (4x float4), 2x MLP vs previous version.
static constexpr int H_PAIRS = MB_TILES * (K_TILES32 / 2);   // 32768
static constexpr int W_PAIRS = NB_TILES * (K_TILES32 / 2);   // 4096
static constexpr int PACK_BLOCKS = (H_PAIRS + W_PAIRS) / 4;  // 9216

__global__ __launch_bounds__(256)
void pack_kernel(const float* __restrict__ X, const int* __restrict__ Mask,
                 const float* __restrict__ W, u16* __restrict__ Ht, u16* __restrict__ Wt) {
  const int l     = threadIdx.x & 63;
  const int pi    = blockIdx.x * 4 + (threadIdx.x >> 6);
  const int row16 = l & 15;
  const int kof   = (l >> 4) << 4;          // 0,16,32,48 within the 64-k pair

  // destination fragment within the pair and 8-k slot inside the fragment
  const int fsub = kof >> 5;                // 0 or 1
  const int q0   = (kof & 31) >> 3;         // 0 or 2

  if (pi < H_PAIRS) {
    const int mb = pi >> 6, kp = pi & 63;
    const size_t src = (size_t)(mb * 16 + row16) * K_DIM + kp * 64 + kof;
    const float* xp = X    + src;
    const int*   mp = Mask + src;
    float4 x0 = *(const float4*)(xp + 0);
    float4 x1 = *(const float4*)(xp + 4);
    float4 x2 = *(const float4*)(xp + 8);
    float4 x3 = *(const float4*)(xp + 12);
    uint4  m0 = *(const uint4*)(mp + 0);
    uint4  m1 = *(const uint4*)(mp + 4);
    uint4  m2 = *(const uint4*)(mp + 8);
    uint4  m3 = *(const uint4*)(mp + 12);
    u32 o0 = pack2(gelu_drop(x0.x, m0.x), gelu_drop(x0.y, m0.y));
    u32 o1 = pack2(gelu_drop(x0.z, m0.z), gelu_drop(x0.w, m0.w));
    u32 o2 = pack2(gelu_drop(x1.x, m1.x), gelu_drop(x1.y, m1.y));
    u32 o3 = pack2(gelu_drop(x1.z, m1.z), gelu_drop(x1.w, m1.w));
    u32 o4 = pack2(gelu_drop(x2.x, m2.x), gelu_drop(x2.y, m2.y));
    u32 o5 = pack2(gelu_drop(x2.z, m2.z), gelu_drop(x2.w, m2.w));
    u32 o6 = pack2(gelu_drop(x3.x, m3.x), gelu_drop(x3.y, m3.y));
    u32 o7 = pack2(gelu_drop(x3.z, m3.z), gelu_drop(x3.w, m3.w));
    const int f = kp * 2 + fsub;
    u16* dst = Ht + (size_t)(mb * 128 + f) * FRAG_U16 + (size_t)(row16 + 16 * q0) * 8;
    *(uint4*)(dst)       = make_uint4(o0, o1, o2, o3);   // slots q0, q0+1? no: 8 halfs = slot q0
    *(uint4*)(dst + 128) = make_uint4(o4, o5, o6, o7);   // slot q0+1 (+256 B)
  } else {
    const int pj = pi - H_PAIRS;
    const int nb = pj >> 6, kp = pj & 63;
    const float* wp = W + (size_t)(nb * 16 + row16) * K_DIM + kp * 64 + kof;
    float4 w0 = *(const float4*)(wp + 0);
    float4 w1 = *(const float4*)(wp + 4);
    float4 w2 = *(const float4*)(wp + 8);
    float4 w3 = *(const float4*)(wp + 12);
    const int f = kp * 2 + fsub;
    u16* dst = Wt + (size_t)(nb * 128 + f) * FRAG_U16 + (size_t)(row16 + 16 * q0) * 8;
    *(uint4*)(dst)       = make_uint4(pack2(w0.x, w0.y), pack2(w0.z, w0.w),
                                      pack2(w1.x, w1.y), pack2(w1.z, w1.w));
    *(uint4*)(dst + 128) = make_uint4(pack2(w2.x, w2.y), pack2(w2.z, w2.w),
                                      pack2(w3.x, w3.y), pack2(w3.z, w3.w));
  }
}

// ---------------- pass 2: 256x128 tile, 3-buffer LDS pipeline, counted vmcnt ----------------
// T3+T4: one raw s_barrier per 64-k tile, s_waitcnt vmcnt(6) in steady state (the 6 loads of
// the newest stage stay in flight across the barrier). T5: setprio around MFMA clusters.
__global__ __launch_bounds__(512, 1)
void gemm_kernel(const u16* __restrict__ Ht, const u16* __restrict__ Wt,
                 const float* __restrict__ Bias, float* __restrict__ Out) {
  __shared__ __attribute__((aligned(16))) u16 Abuf[3][BM * BK];  // 3 x 32 KiB
  __shared__ __attribute__((aligned(16))) u16 Bbuf[3][BN * BK];  // 3 x 16 KiB -> 144 KiB total

  const int tid  = threadIdx.x;
  const int lane = tid & 63;
  const int wv   = tid >> 6;   // 0..7
  const int wr   = wv >> 1;    // m quarter 0..3 (64 rows each)
  const int wc   = wv & 1;     // n half 0..1 (64 cols each)

  // bm fast -> the 8 bn-blocks sharing a row-stripe land on one XCD (%8): A is L2-shared x8.
  const int bm = blockIdx.x & 31;
  const int bn = blockIdx.x >> 5;
  const int m0 = bm * BM;
  const int n0 = bn * BN;

  // ---- staging source offsets (frag-major ws layout) ----
  const char* aG = (const char*)Ht;
  const char* bG = (const char*)Wt;
  size_t aOff[4], bOff[2];
#pragma unroll
  for (int p = 0; p < 4; ++p) {
    const int s = tid + 512 * p, f = s >> 6;
    aOff[p] = ((size_t)(bm * 16 + (f >> 1)) * K_TILES32 + (f & 1)) * 1024 + (size_t)(s & 63) * 16;
  }
#pragma unroll
  for (int p = 0; p < 2; ++p) {
    const int s = tid + 512 * p, f = s >> 6;
    bOff[p] = ((size_t)(bn * 8 + (f >> 1)) * K_TILES32 + (f & 1)) * 1024 + (size_t)(s & 63) * 16;
  }

  auto stage = [&](int kt, int buf) {
    const size_t ko = (size_t)kt * 2048;   // advance 2 k-frags (2 KiB) per 64-k tile
    char* ad = (char*)Abuf[buf];
    char* bd = (char*)Bbuf[buf];
#pragma unroll
    for (int p = 0; p < 4; ++p)
      async_cp16(aG + aOff[p] + ko, ad + (tid + 512 * p) * 16);
#pragma unroll
    for (int p = 0; p < 2; ++p)
      async_cp16(bG + bOff[p] + ko, bd + (tid + 512 * p) * 16);
  };

  f32x4 acc[4][4];
#pragma unroll
  for (int i = 0; i < 4; ++i)
#pragma unroll
    for (int j = 0; j < 4; ++j)
      acc[i][j] = (f32x4){0.f, 0.f, 0.f, 0.f};

  auto compute = [&](int buf) {
    const char* ab = (const char*)Abuf[buf];
    const char* bb = (const char*)Bbuf[buf];
#pragma unroll
    for (int kk = 0; kk < 2; ++kk) {
      half8 ar[4], br[4];
#pragma unroll
      for (int i = 0; i < 4; ++i)
        ar[i] = *(const half8*)(ab + (((wr * 4 + i) * 2 + kk) * 64 + lane) * 16);
#pragma unroll
      for (int j = 0; j < 4; ++j)
        br[j] = *(const half8*)(bb + (((wc * 4 + j) * 2 + kk) * 64 + lane) * 16);
      __builtin_amdgcn_s_setprio(1);
#pragma unroll
      for (int i = 0; i < 4; ++i)
#pragma unroll
        for (int j = 0; j < 4; ++j)
          acc[i][j] = __builtin_amdgcn_mfma_f32_16x16x32_f16(ar[i], br[j], acc[i][j], 0, 0, 0);
      __builtin_amdgcn_s_setprio(0);
    }
  };

  // prologue: 2-deep prefetch
  stage(0, 0);
  stage(1, 1);

  int cur = 0;
#pragma unroll 1
  for (int kt = 0; kt < KT64; ++kt) {
    if (kt + 2 < KT64) {
      // stage(kt) fully landed (6 newest outstanding = stage(kt+1)); kt+1 stays in flight
      asm volatile("s_waitcnt vmcnt(6)" ::: "memory");
      __builtin_amdgcn_s_barrier();
      asm volatile("" ::: "memory");
      stage(kt + 2, cur == 0 ? 2 : cur - 1);   // (kt+2) % 3
    } else if (kt + 1 < KT64) {
      asm volatile("s_waitcnt vmcnt(6)" ::: "memory");
      __builtin_amdgcn_s_barrier();
      asm volatile("" ::: "memory");
    } else {
      asm volatile("s_waitcnt vmcnt(0)" ::: "memory");
      __builtin_amdgcn_s_barrier();
      asm volatile("" ::: "memory");
    }
    compute(cur);
    cur = (cur == 2) ? 0 : cur + 1;
  }

  // ---- epilogue: C/D layout col = lane&15, row = (lane>>4)*4 + reg  [verified R3-R6] ----
  const int fr = lane & 15;
  const int rq = (lane >> 4) << 2;
  float bv[4];
#pragma unroll
  for (int j = 0; j < 4; ++j)
    bv[j] = Bias[n0 + wc * 64 + j * 16 + fr];

#pragma unroll
  for (int i = 0; i < 4; ++i) {
    const int row0 = m0 + wr * 64 + i * 16 + rq;
#pragma unroll
    for (int j = 0; j < 4; ++j) {
      const int col = n0 + wc * 64 + j * 16 + fr;
#pragma unroll
      for (int r = 0; r < 4; ++r)
        Out[(size_t)(row0 + r) * N_DIM + col] = acc[i][j][r] + bv[j];
    }
  }
}

// ---------------- fallback: verified R3 fused kernel (only if ws too small) ----------------
static constexpr int A_STRIDE = 40;

__global__ __launch_bounds__(256, 2)
void fused_fallback_kernel(const float* __restrict__ X, const float* __restrict__ W,
                           const float* __restrict__ Bias, const int* __restrict__ Mask,
                           float* __restrict__ Out) {
  __shared__ __attribute__((aligned(16))) _Float16 As[128 * A_STRIDE];
  __shared__ __attribute__((aligned(16))) _Float16 Bs[128 * 32];

  const int tid  = threadIdx.x;
  const int lane = tid & 63;
  const int wv   = tid >> 6;
  const int wr   = wv >> 1;
  const int wc   = wv & 1;
  const int bm = blockIdx.x & 63;
  const int bn = blockIdx.x >> 6;
  const int m0 = bm * 128;
  const int n0 = bn * 128;

  const int a_m = tid >> 1;
  const int a_k = (tid & 1) << 4;
  const float* xptr = X    + (size_t)(m0 + a_m) * K_DIM + a_k;
  const int*   mptr = Mask + (size_t)(m0 + a_m) * K_DIM + a_k;
  _Float16* a_lds = &As[a_m * A_STRIDE + a_k];

  const int i0 = tid, i1 = tid + 256;
  const float* wp0 = W + (size_t)(n0 + (i0 >> 2)) * K_DIM + ((i0 & 3) << 3);
  const float* wp1 = W + (size_t)(n0 + (i1 >> 2)) * K_DIM + ((i1 & 3) << 3);
  _Float16* bl0 = &Bs[i0 * 8];
  _Float16* bl1 = &Bs[i1 * 8];

  f32x4 acc[4][4];
#pragma unroll
  for (int i = 0; i < 4; ++i)
#pragma unroll
    for (int j = 0; j < 4; ++j)
      acc[i][j] = (f32x4){0.f, 0.f, 0.f, 0.f};

  float4 xf0 = *(const float4*)(xptr +  0);
  float4 xf1 = *(const float4*)(xptr +  4);
  float4 xf2 = *(const float4*)(xptr +  8);
  float4 xf3 = *(const float4*)(xptr + 12);
  uint4  mr0 = *(const uint4*)(mptr +  0);
  uint4  mr1 = *(const uint4*)(mptr +  4);
  uint4  mr2 = *(const uint4*)(mptr +  8);
  uint4  mr3 = *(const uint4*)(mptr + 12);
  float4 wf0 = *(const float4*)(wp0 + 0);
  float4 wf1 = *(const float4*)(wp0 + 4);
  float4 wf2 = *(const float4*)(wp1 + 0);
  float4 wf3 = *(const float4*)(wp1 + 4);

#pragma unroll 1
  for (int kt = 0; kt < 128; ++kt) {
    {
      float xs[16] = {xf0.x, xf0.y, xf0.z, xf0.w, xf1.x, xf1.y, xf1.z, xf1.w,
                      xf2.x, xf2.y, xf2.z, xf2.w, xf3.x, xf3.y, xf3.z, xf3.w};
      u32 mk[16]   = {mr0.x, mr0.y, mr0.z, mr0.w, mr1.x, mr1.y, mr1.z, mr1.w,
                      mr2.x, mr2.y, mr2.z, mr2.w, mr3.x, mr3.y, mr3.z, mr3.w};
      u32 ow[8];
#pragma unroll
      for (int e = 0; e < 8; ++e)
        ow[e] = pack2(gelu_drop(xs[2 * e], mk[2 * e]), gelu_drop(xs[2 * e + 1], mk[2 * e + 1]));
      ((uint4*)a_lds)[0] = make_uint4(ow[0], ow[1], ow[2], ow[3]);
      ((uint4*)a_lds)[1] = make_uint4(ow[4], ow[5], ow[6], ow[7]);
    }
    {
      *(uint4*)bl0 = make_uint4(pack2(wf0.x, wf0.y), pack2(wf0.z, wf0.w),
                                pack2(wf1.x, wf1.y), pack2(wf1.z, wf1.w));
      *(uint4*)bl1 = make_uint4(pack2(wf2.x, wf2.y), pack2(wf2.z, wf2.w),
                                pack2(wf3.x, wf3.y), pack2(wf3.z, wf3.w));
    }
    __syncthreads();

    if (kt + 1 < 128) {
      xptr += 32; mptr += 32; wp0 += 32; wp1 += 32;
      xf0 = *(const float4*)(xptr +  0);
      xf1 = *(const float4*)(xptr +  4);
      xf2 = *(const float4*)(xptr +  8);
      xf3 = *(const float4*)(xptr + 12);
      mr0 = *(const uint4*)(mptr +  0);
      mr1 = *(const uint4*)(mptr +  4);
      mr2 = *(const uint4*)(mptr +  8);
      mr3 = *(const uint4*)(mptr + 12);
      wf0 = *(const float4*)(wp0 + 0);
      wf1 = *(const float4*)(wp0 + 4);
      wf2 = *(const float4*)(wp1 + 0);
      wf3 = *(const float4*)(wp1 + 4);
    }

    {
      const int fr2 = lane & 15;
      const int fk2 = (lane >> 4) << 3;
      half8 ar[4], br[4];
#pragma unroll
      for (int i = 0; i < 4; ++i)
        ar[i] = *(const half8*)&As[(wr * 64 + i * 16 + fr2) * A_STRIDE + fk2];
#pragma unroll
      for (int j = 0; j < 4; ++j)
        br[j] = *(const half8*)&Bs[(wc * 64 + j * 16 + fr2) * 32 + fk2];
#pragma unroll
      for (int i = 0; i < 4; ++i)
#pragma unroll
        for (int j = 0; j < 4; ++j)
          acc[i][j] = __builtin_amdgcn_mfma_f32_16x16x32_f16(ar[i], br[j], acc[i][j], 0, 0, 0);
    }
    __syncthreads();
  }

  const int fr = lane & 15;
  const int rq = (lane >> 4) << 2;
  float bv[4];
#pragma unroll
  for (int j = 0; j < 4; ++j)
    bv[j] = Bias[n0 + wc * 64 + j * 16 + fr];
#pragma unroll
  for (int i = 0; i < 4; ++i) {
    const int row0 = m0 + wr * 64 + i * 16 + rq;
#pragma unroll
    for (int j = 0; j < 4; ++j) {
      const int col = n0 + wc * 64 + j * 16 + fr;
#pragma unroll
      for (int r = 0; r < 4; ++r)
        Out[(size_t)(row0 + r) * N_DIM + col] = acc[i][j][r] + bv[j];
    }
  }
}

extern "C" void kernel_launch(void* const* d_in, const int* in_sizes, int n_in,
                              void* d_out, int out_size, void* d_ws, size_t ws_size,
                              hipStream_t stream) {
  const float* X    = (const float*)d_in[0];   // x (8192x4096), fp16 canonicalized to f32
  const float* W    = (const float*)d_in[1];   // weight (1024x4096) f32, K-contiguous
  const float* Bias = (const float*)d_in[2];   // bias (1024) f32
  const int*   Mk   = (const int*)d_in[3];     // keep-mask int32 0/1
  float* Out = (float*)d_out;                  // y (8192x1024) f32

  if (ws_size >= WS_NEEDED) {
    u16* Ht = (u16*)d_ws;
    u16* Wt = (u16*)((char*)d_ws + HT_BYTES);
    pack_kernel<<<PACK_BLOCKS, 256, 0, stream>>>(X, Mk, W, Ht, Wt);
    gemm_kernel<<<(M_DIM / BM) * (N_DIM / BN), 512, 0, stream>>>(Ht, Wt, Bias, Out);  // 256 blocks
  } else {
    fused_fallback_kernel<<<64 * 8, 256, 0, stream>>>(X, W, Bias, Mk, Out);
  }
}

// Round 2
// 389.034 us; speedup vs baseline: 1.0313x; 1.0313x over previous
//
#include <hip/hip_runtime.h>
#include <stdint.h>

typedef uint32_t u32;
typedef uint16_t u16;

static constexpr int M_DIM = 8192;
static constexpr int N_DIM = 1024;
static constexpr int K_DIM = 4096;

// gemm geometry: 256x128 tile, BK=64, 1 block/CU, both operands through LDS
static constexpr int BM = 256;
static constexpr int BN = 128;
static constexpr int BK = 64;
static constexpr int KT64 = K_DIM / BK;          // 64 k-tiles
static constexpr int K_TILES32 = K_DIM / 32;     // 128 32-k fragments along K
static constexpr int MB_TILES = M_DIM / 16;      // 512
static constexpr int NB_TILES = N_DIM / 16;      // 64

// fragment = 16 rows x 32 k fp16 in exact MFMA lane order: 64 lanes x 16 B = 1 KiB
static constexpr size_t FRAG_U16 = 512;
static constexpr size_t HT_BYTES = (size_t)MB_TILES * K_TILES32 * FRAG_U16 * 2;  // 64 MiB
static constexpr size_t WT_BYTES = (size_t)NB_TILES * K_TILES32 * FRAG_U16 * 2;  // 8 MiB
static constexpr size_t WS_NEEDED = HT_BYTES + WT_BYTES;                         // 72 MiB

typedef __attribute__((ext_vector_type(8))) _Float16 half8;  // MFMA A/B frag (4 VGPRs)
typedef __attribute__((ext_vector_type(4))) float f32x4;     // MFMA C/D frag

__device__ __forceinline__ u32 pack2(float a, float b) {
  union { _Float16 h[2]; u32 u; } p;
  p.h[0] = (_Float16)a;   // v_cvt_f16_f32, RNE
  p.h[1] = (_Float16)b;
  return p.u;
}

// GELU via Abramowitz-Stegun 7.1.26 erf (|err| <= 1.5e-7) + dropout keep-mask * 1/(1-0.1).
__device__ __forceinline__ float gelu_drop(float x, u32 keep) {
  float ax = fabsf(x);
  float z  = ax * 0.70710678f;
  float t  = __builtin_amdgcn_rcpf(fmaf(0.3275911f, z, 1.0f));
  float poly = fmaf(fmaf(fmaf(fmaf(1.061405429f, t, -1.453152027f),
                              t, 1.421413741f),
                         t, -0.284496736f),
                    t, 0.254829592f) * t;
  float e   = exp2f(z * z * -1.44269504f);    // exp(-z^2)
  float erf = fmaf(-poly, e, 1.0f);           // erf(|x|/sqrt(2)) in [0,1)
  float g   = 0.5f * x * (1.0f + copysignf(erf, x));
  return keep ? g * 1.1111112f : 0.0f;
}

__device__ __forceinline__ void async_cp16(const void* g, void* l) {
  __builtin_amdgcn_global_load_lds((__attribute__((address_space(1))) u32*)g,
                                   (__attribute__((address_space(3))) u32*)l,
                                   16, 0, 0);
}

// ---------------- pass 1: fragment-major pack, kt-PAIR per wave (unchanged from R1) ----------------
static constexpr int H_PAIRS = MB_TILES * (K_TILES32 / 2);   // 32768
static constexpr int W_PAIRS = NB_TILES * (K_TILES32 / 2);   // 4096
static constexpr int PACK_BLOCKS = (H_PAIRS + W_PAIRS) / 4;  // 9216

__global__ __launch_bounds__(256)
void pack_kernel(const float* __restrict__ X, const int* __restrict__ Mask,
                 const float* __restrict__ W, u16* __restrict__ Ht, u16* __restrict__ Wt) {
  const int l     = threadIdx.x & 63;
  const int pi    = blockIdx.x * 4 + (threadIdx.x >> 6);
  const int row16 = l & 15;
  const int kof   = (l >> 4) << 4;          // 0,16,32,48 within the 64-k pair

  const int fsub = kof >> 5;                // 0 or 1
  const int q0   = (kof & 31) >> 3;         // 0 or 2

  if (pi < H_PAIRS) {
    const int mb = pi >> 6, kp = pi & 63;
    const size_t src = (size_t)(mb * 16 + row16) * K_DIM + kp * 64 + kof;
    const float* xp = X    + src;
    const int*   mp = Mask + src;
    float4 x0 = *(const float4*)(xp + 0);
    float4 x1 = *(const float4*)(xp + 4);
    float4 x2 = *(const float4*)(xp + 8);
    float4 x3 = *(const float4*)(xp + 12);
    uint4  m0 = *(const uint4*)(mp + 0);
    uint4  m1 = *(const uint4*)(mp + 4);
    uint4  m2 = *(const uint4*)(mp + 8);
    uint4  m3 = *(const uint4*)(mp + 12);
    u32 o0 = pack2(gelu_drop(x0.x, m0.x), gelu_drop(x0.y, m0.y));
    u32 o1 = pack2(gelu_drop(x0.z, m0.z), gelu_drop(x0.w, m0.w));
    u32 o2 = pack2(gelu_drop(x1.x, m1.x), gelu_drop(x1.y, m1.y));
    u32 o3 = pack2(gelu_drop(x1.z, m1.z), gelu_drop(x1.w, m1.w));
    u32 o4 = pack2(gelu_drop(x2.x, m2.x), gelu_drop(x2.y, m2.y));
    u32 o5 = pack2(gelu_drop(x2.z, m2.z), gelu_drop(x2.w, m2.w));
    u32 o6 = pack2(gelu_drop(x3.x, m3.x), gelu_drop(x3.y, m3.y));
    u32 o7 = pack2(gelu_drop(x3.z, m3.z), gelu_drop(x3.w, m3.w));
    const int f = kp * 2 + fsub;
    u16* dst = Ht + (size_t)(mb * 128 + f) * FRAG_U16 + (size_t)(row16 + 16 * q0) * 8;
    *(uint4*)(dst)       = make_uint4(o0, o1, o2, o3);
    *(uint4*)(dst + 128) = make_uint4(o4, o5, o6, o7);
  } else {
    const int pj = pi - H_PAIRS;
    const int nb = pj >> 6, kp = pj & 63;
    const float* wp = W + (size_t)(nb * 16 + row16) * K_DIM + kp * 64 + kof;
    float4 w0 = *(const float4*)(wp + 0);
    float4 w1 = *(const float4*)(wp + 4);
    float4 w2 = *(const float4*)(wp + 8);
    float4 w3 = *(const float4*)(wp + 12);
    const int f = kp * 2 + fsub;
    u16* dst = Wt + (size_t)(nb * 128 + f) * FRAG_U16 + (size_t)(row16 + 16 * q0) * 8;
    *(uint4*)(dst)       = make_uint4(pack2(w0.x, w0.y), pack2(w0.z, w0.w),
                                      pack2(w1.x, w1.y), pack2(w1.z, w1.w));
    *(uint4*)(dst + 128) = make_uint4(pack2(w2.x, w2.y), pack2(w2.z, w2.w),
                                      pack2(w3.x, w3.y), pack2(w3.z, w3.w));
  }
}

// ---------------- pass 2: 256x128, m201-style per-phase interleave (T3+T4+T5) ----------------
// Per K-tile: 2 phases. Each phase: {8 ds_read_b128 || issue 3 global_load_lds} -> s_barrier ->
// lgkmcnt(0)+sched_barrier(0) -> setprio(1) -> 16 MFMA -> setprio(0) -> s_barrier.
// vmcnt(6) exactly once per K-tile (phase B): the newest tile's 6 loads stay in flight.
__global__ __launch_bounds__(512, 1)
void gemm_kernel(const u16* __restrict__ Ht, const u16* __restrict__ Wt,
                 const float* __restrict__ Bias, float* __restrict__ Out) {
  __shared__ __attribute__((aligned(16))) u16 Abuf[3][BM * BK];  // 3 x 32 KiB
  __shared__ __attribute__((aligned(16))) u16 Bbuf[3][BN * BK];  // 3 x 16 KiB -> 144 KiB total

  const int tid  = threadIdx.x;
  const int lane = tid & 63;
  const int wv   = tid >> 6;   // 0..7
  const int wr   = wv >> 1;    // m quarter 0..3 (64 rows each)
  const int wc   = wv & 1;     // n half 0..1 (64 cols each)

  // bm fast -> the 8 bn-blocks sharing a row-stripe land on one XCD (%8): A is L2-shared x8.
  const int bm = blockIdx.x & 31;
  const int bn = blockIdx.x >> 5;
  const int m0 = bm * BM;
  const int n0 = bn * BN;

  // ---- staging source offsets (frag-major ws layout) ----
  const char* aG = (const char*)Ht;
  const char* bG = (const char*)Wt;
  size_t aOff[4], bOff[2];
#pragma unroll
  for (int p = 0; p < 4; ++p) {
    const int s = tid + 512 * p, f = s >> 6;
    aOff[p] = ((size_t)(bm * 16 + (f >> 1)) * K_TILES32 + (f & 1)) * 1024 + (size_t)(s & 63) * 16;
  }
#pragma unroll
  for (int p = 0; p < 2; ++p) {
    const int s = tid + 512 * p, f = s >> 6;
    bOff[p] = ((size_t)(bn * 8 + (f >> 1)) * K_TILES32 + (f & 1)) * 1024 + (size_t)(s & 63) * 16;
  }

  // half h=0: aOff[0],aOff[1],bOff[0]; half h=1: aOff[2],aOff[3],bOff[1]  (3 loads each)
  auto stageHalf = [&](int kt, int buf, int h) {
    const size_t ko = (size_t)kt * 2048;
    char* ad = (char*)Abuf[buf];
    char* bd = (char*)Bbuf[buf];
    if (h == 0) {
      async_cp16(aG + aOff[0] + ko, ad + (size_t)(tid)*16);
      async_cp16(aG + aOff[1] + ko, ad + (size_t)(tid + 512) * 16);
      async_cp16(bG + bOff[0] + ko, bd + (size_t)(tid)*16);
    } else {
      async_cp16(aG + aOff[2] + ko, ad + (size_t)(tid + 1024) * 16);
      async_cp16(aG + aOff[3] + ko, ad + (size_t)(tid + 1536) * 16);
      async_cp16(bG + bOff[1] + ko, bd + (size_t)(tid + 512) * 16);
    }
  };

  auto stageFull = [&](int kt, int buf) {
    stageHalf(kt, buf, 0);
    stageHalf(kt, buf, 1);
  };

  f32x4 acc[4][4];
#pragma unroll
  for (int i = 0; i < 4; ++i)
#pragma unroll
    for (int j = 0; j < 4; ++j)
      acc[i][j] = (f32x4){0.f, 0.f, 0.f, 0.f};

  // one phase: ds_read subtile (kk) || stage half -> barrier -> MFMA cluster -> barrier
  // vm: -1 = no wait, otherwise "s_waitcnt vmcnt(vm)" just before the pre-MFMA barrier.
  auto phase = [&](int buf, int kk, int stKt, int stBuf, int h, int vm) {
    const char* ab = (const char*)Abuf[buf];
    const char* bb = (const char*)Bbuf[buf];
    half8 ar[4], br[4];
#pragma unroll
    for (int i = 0; i < 4; ++i)
      ar[i] = *(const half8*)(ab + (size_t)(((wr * 4 + i) * 2 + kk) * 64 + lane) * 16);
#pragma unroll
    for (int j = 0; j < 4; ++j)
      br[j] = *(const half8*)(bb + (size_t)(((wc * 4 + j) * 2 + kk) * 64 + lane) * 16);
    if (stKt >= 0) stageHalf(stKt, stBuf, h);
    if (vm == 6) asm volatile("s_waitcnt vmcnt(6)" ::: "memory");
    else if (vm == 0) asm volatile("s_waitcnt vmcnt(0)" ::: "memory");
    __builtin_amdgcn_s_barrier();
    asm volatile("s_waitcnt lgkmcnt(0)" ::: "memory");
    __builtin_amdgcn_sched_barrier(0);
    __builtin_amdgcn_s_setprio(1);
#pragma unroll
    for (int i = 0; i < 4; ++i)
#pragma unroll
      for (int j = 0; j < 4; ++j)
        acc[i][j] = __builtin_amdgcn_mfma_f32_16x16x32_f16(ar[i], br[j], acc[i][j], 0, 0, 0);
    __builtin_amdgcn_s_setprio(0);
    __builtin_amdgcn_sched_barrier(0);
    __builtin_amdgcn_s_barrier();
  };

  // prologue: 2-deep prefetch; ensure tile 0 landed (tile 1's 6 loads stay in flight)
  stageFull(0, 0);
  stageFull(1, 1);
  asm volatile("s_waitcnt vmcnt(6)" ::: "memory");
  __builtin_amdgcn_s_barrier();

#pragma unroll 1
  for (int kt = 0; kt < KT64; ++kt) {
    const int cur  = kt % 3;
    const bool st  = (kt + 2) < KT64;
    const int  sb  = (kt + 2) % 3;
    // per-tile vmcnt: drain the (kt+1) tile's 6 loads; keep (kt+2)'s 6 in flight.
    const int vm = st ? 6 : ((kt + 1) < KT64 ? 0 : -1);
    phase(cur, 0, st ? kt + 2 : -1, sb, 0, -1);   // phase A: kk=0, stage half 0
    phase(cur, 1, st ? kt + 2 : -1, sb, 1, vm);   // phase B: kk=1, stage half 1, vmcnt
  }

  // ---- epilogue: C/D layout col = lane&15, row = (lane>>4)*4 + reg  [verified R3-R6] ----
  const int fr = lane & 15;
  const int rq = (lane >> 4) << 2;
  float bv[4];
#pragma unroll
  for (int j = 0; j < 4; ++j)
    bv[j] = Bias[n0 + wc * 64 + j * 16 + fr];

#pragma unroll
  for (int i = 0; i < 4; ++i) {
    const int row0 = m0 + wr * 64 + i * 16 + rq;
#pragma unroll
    for (int j = 0; j < 4; ++j) {
      const int col = n0 + wc * 64 + j * 16 + fr;
#pragma unroll
      for (int r = 0; r < 4; ++r)
        Out[(size_t)(row0 + r) * N_DIM + col] = acc[i][j][r] + bv[j];
    }
  }
}

// ---------------- fallback: verified R3 fused kernel (only if ws too small) ----------------
static constexpr int A_STRIDE = 40;

__global__ __launch_bounds__(256, 2)
void fused_fallback_kernel(const float* __restrict__ X, const float* __restrict__ W,
                           const float* __restrict__ Bias, const int* __restrict__ Mask,
                           float* __restrict__ Out) {
  __shared__ __attribute__((aligned(16))) _Float16 As[128 * A_STRIDE];
  __shared__ __attribute__((aligned(16))) _Float16 Bs[128 * 32];

  const int tid  = threadIdx.x;
  const int lane = tid & 63;
  const int wv   = tid >> 6;
  const int wr   = wv >> 1;
  const int wc   = wv & 1;
  const int bm = blockIdx.x & 63;
  const int bn = blockIdx.x >> 6;
  const int m0 = bm * 128;
  const int n0 = bn * 128;

  const int a_m = tid >> 1;
  const int a_k = (tid & 1) << 4;
  const float* xptr = X    + (size_t)(m0 + a_m) * K_DIM + a_k;
  const int*   mptr = Mask + (size_t)(m0 + a_m) * K_DIM + a_k;
  _Float16* a_lds = &As[a_m * A_STRIDE + a_k];

  const int i0 = tid, i1 = tid + 256;
  const float* wp0 = W + (size_t)(n0 + (i0 >> 2)) * K_DIM + ((i0 & 3) << 3);
  const float* wp1 = W + (size_t)(n0 + (i1 >> 2)) * K_DIM + ((i1 & 3) << 3);
  _Float16* bl0 = &Bs[i0 * 8];
  _Float16* bl1 = &Bs[i1 * 8];

  f32x4 acc[4][4];
#pragma unroll
  for (int i = 0; i < 4; ++i)
#pragma unroll
    for (int j = 0; j < 4; ++j)
      acc[i][j] = (f32x4){0.f, 0.f, 0.f, 0.f};

  float4 xf0 = *(const float4*)(xptr +  0);
  float4 xf1 = *(const float4*)(xptr +  4);
  float4 xf2 = *(const float4*)(xptr +  8);
  float4 xf3 = *(const float4*)(xptr + 12);
  uint4  mr0 = *(const uint4*)(mptr +  0);
  uint4  mr1 = *(const uint4*)(mptr +  4);
  uint4  mr2 = *(const uint4*)(mptr +  8);
  uint4  mr3 = *(const uint4*)(mptr + 12);
  float4 wf0 = *(const float4*)(wp0 + 0);
  float4 wf1 = *(const float4*)(wp0 + 4);
  float4 wf2 = *(const float4*)(wp1 + 0);
  float4 wf3 = *(const float4*)(wp1 + 4);

#pragma unroll 1
  for (int kt = 0; kt < 128; ++kt) {
    {
      float xs[16] = {xf0.x, xf0.y, xf0.z, xf0.w, xf1.x, xf1.y, xf1.z, xf1.w,
                      xf2.x, xf2.y, xf2.z, xf2.w, xf3.x, xf3.y, xf3.z, xf3.w};
      u32 mk[16]   = {mr0.x, mr0.y, mr0.z, mr0.w, mr1.x, mr1.y, mr1.z, mr1.w,
                      mr2.x, mr2.y, mr2.z, mr2.w, mr3.x, mr3.y, mr3.z, mr3.w};
      u32 ow[8];
#pragma unroll
      for (int e = 0; e < 8; ++e)
        ow[e] = pack2(gelu_drop(xs[2 * e], mk[2 * e]), gelu_drop(xs[2 * e + 1], mk[2 * e + 1]));
      ((uint4*)a_lds)[0] = make_uint4(ow[0], ow[1], ow[2], ow[3]);
      ((uint4*)a_lds)[1] = make_uint4(ow[4], ow[5], ow[6], ow[7]);
    }
    {
      *(uint4*)bl0 = make_uint4(pack2(wf0.x, wf0.y), pack2(wf0.z, wf0.w),
                                pack2(wf1.x, wf1.y), pack2(wf1.z, wf1.w));
      *(uint4*)bl1 = make_uint4(pack2(wf2.x, wf2.y), pack2(wf2.z, wf2.w),
                                pack2(wf3.x, wf3.y), pack2(wf3.z, wf3.w));
    }
    __syncthreads();

    if (kt + 1 < 128) {
      xptr += 32; mptr += 32; wp0 += 32; wp1 += 32;
      xf0 = *(const float4*)(xptr +  0);
      xf1 = *(const float4*)(xptr +  4);
      xf2 = *(const float4*)(xptr +  8);
      xf3 = *(const float4*)(xptr + 12);
      mr0 = *(const uint4*)(mptr +  0);
      mr1 = *(const uint4*)(mptr +  4);
      mr2 = *(const uint4*)(mptr +  8);
      mr3 = *(const uint4*)(mptr + 12);
      wf0 = *(const float4*)(wp0 + 0);
      wf1 = *(const float4*)(wp0 + 4);
      wf2 = *(const float4*)(wp1 + 0);
      wf3 = *(const float4*)(wp1 + 4);
    }

    {
      const int fr2 = lane & 15;
      const int fk2 = (lane >> 4) << 3;
      half8 ar[4], br[4];
#pragma unroll
      for (int i = 0; i < 4; ++i)
        ar[i] = *(const half8*)&As[(wr * 64 + i * 16 + fr2) * A_STRIDE + fk2];
#pragma unroll
      for (int j = 0; j < 4; ++j)
        br[j] = *(const half8*)&Bs[(wc * 64 + j * 16 + fr2) * 32 + fk2];
#pragma unroll
      for (int i = 0; i < 4; ++i)
#pragma unroll
        for (int j = 0; j < 4; ++j)
          acc[i][j] = __builtin_amdgcn_mfma_f32_16x16x32_f16(ar[i], br[j], acc[i][j], 0, 0, 0);
    }
    __syncthreads();
  }

  const int fr = lane & 15;
  const int rq = (lane >> 4) << 2;
  float bv[4];
#pragma unroll
  for (int j = 0; j < 4; ++j)
    bv[j] = Bias[n0 + wc * 64 + j * 16 + fr];
#pragma unroll
  for (int i = 0; i < 4; ++i) {
    const int row0 = m0 + wr * 64 + i * 16 + rq;
#pragma unroll
    for (int j = 0; j < 4; ++j) {
      const int col = n0 + wc * 64 + j * 16 + fr;
#pragma unroll
      for (int r = 0; r < 4; ++r)
        Out[(size_t)(row0 + r) * N_DIM + col] = acc[i][j][r] + bv[j];
    }
  }
}

extern "C" void kernel_launch(void* const* d_in, const int* in_sizes, int n_in,
                              void* d_out, int out_size, void* d_ws, size_t ws_size,
                              hipStream_t stream) {
  const float* X    = (const float*)d_in[0];   // x (8192x4096), fp16 canonicalized to f32
  const float* W    = (const float*)d_in[1];   // weight (1024x4096) f32, K-contiguous
  const float* Bias = (const float*)d_in[2];   // bias (1024) f32
  const int*   Mk   = (const int*)d_in[3];     // keep-mask int32 0/1
  float* Out = (float*)d_out;                  // y (8192x1024) f32

  if (ws_size >= WS_NEEDED) {
    u16* Ht = (u16*)d_ws;
    u16* Wt = (u16*)((char*)d_ws + HT_BYTES);
    pack_kernel<<<PACK_BLOCKS, 256, 0, stream>>>(X, Mk, W, Ht, Wt);
    gemm_kernel<<<(M_DIM / BM) * (N_DIM / BN), 512, 0, stream>>>(Ht, Wt, Bias, Out);  // 256 blocks
  } else {
    fused_fallback_kernel<<<64 * 8, 256, 0, stream>>>(X, W, Bias, Mk, Out);
  }
}